// Round 7
// baseline (488.950 us; speedup 1.0000x reference)
//
#include <hip/hip_runtime.h>
#include <hip/hip_cooperative_groups.h>
#include <math.h>

namespace cg = cooperative_groups;

// Problem constants: B=2, H=240, W=1216, ITER=3, NUM=9, CH=27
#define B_ 2
#define H_ 240
#define W_ 1216
#define CH_ 27
#define NUM_ 9
#define PIX_ (B_ * H_ * W_)   // 583680
#define CHP 32                // channel pad in gt
#define CHL 40                // channel pad in LDS (bf16)
#define TX 32
#define TY 8
#define HALO_W (TX + 2)       // 34
#define HALO_H (TY + 2)       // 10
#define NPX (HALO_H * HALO_W) // 340
#define SCS 27                // sC stride (gcd(27,32)=1 -> conflict-free)
#define NTILES (38 * 30 * B_) // 2280

typedef __attribute__((ext_vector_type(8))) __bf16 bf16x8;
typedef __attribute__((ext_vector_type(16))) float f32x16;

// ---------------------------------------------------------------------------
// Persistent cooperative kernel: ONE dispatch for the whole module.
// Phase 0 (grid-stride): guide NCHW fp32 -> gt [pix][32] bf16; conv_w -> wlin.
// grid.sync(). Then 3 propagation epochs with grid.sync() between.
// Grid size is capacity-clamped at launch; tile loop is grid-stride so any
// grid size is correct.
// ---------------------------------------------------------------------------
__global__ __launch_bounds__(256, 4) void dyspn_persistent(
    const float* __restrict__ guide, const float* __restrict__ conv_w,
    const float* __restrict__ conv_b, const float* __restrict__ tap,
    const float* __restrict__ confidence, const float* __restrict__ sp_dep,
    const float* __restrict__ input, float* __restrict__ pred,
    float* __restrict__ feat, float* __restrict__ inter,
    __bf16* __restrict__ gt, __bf16* __restrict__ wlin)
{
    cg::grid_group gg = cg::this_grid();

    // union: sG [340][40] bf16 = 27200 B ; sC [256][27] f32 = 27648 B
    __shared__ __align__(16) char smemA[256 * SCS * 4];
    __bf16* sG = (__bf16*)smemA;
    float*  sC = (float*)smemA;
    __shared__ float sBias[CH_ + 1];
    __shared__ float sTap[18];

    const int tid  = threadIdx.x;
    const int lane = tid & 63;
    const int w    = tid >> 6;
    const int xl   = lane & 31;
    const int half = lane >> 5;
    const int nb   = gridDim.x;
    const int brank = blockIdx.x;

    // ---- phase 0a: transpose guide -> gt (grid-stride, coalesced) ----
    for (int pix = brank * 256 + tid; pix < PIX_; pix += nb * 256) {
        int b = pix / (H_ * W_);
        int off = pix - b * (H_ * W_);
        __align__(16) __bf16 tmp[CHP];
        const float* src = guide + (size_t)b * CH_ * H_ * W_ + off;
        #pragma unroll
        for (int ic = 0; ic < CH_; ++ic)
            tmp[ic] = (__bf16)src[(size_t)ic * (H_ * W_)];
        #pragma unroll
        for (int ic = CH_; ic < CHP; ++ic) tmp[ic] = (__bf16)0.f;
        bf16x8* dst = (bf16x8*)(gt + (size_t)pix * CHP);
        const bf16x8* s8 = (const bf16x8*)tmp;
        #pragma unroll
        for (int c = 0; c < 4; ++c) dst[c] = s8[c];
    }

    // ---- phase 0b: conv_w -> wlin[((it*9+tap)*2+ks)*64 + lane][8] ----
    for (int idx = brank * 256 + tid; idx < 3 * 9 * 2 * 64; idx += nb * 256) {
        int l = idx & 63;
        int grp = idx >> 6;
        int ks = grp & 1;
        int tapi = (grp >> 1) % 9;
        int it = (grp >> 1) / 9;
        int n = l & 31;
        int hf = l >> 5;
        __align__(16) __bf16 v8[8];
        #pragma unroll
        for (int j = 0; j < 8; ++j) {
            int ic = ks * 16 + hf * 8 + j;
            float v = 0.f;
            if (ic < CH_ && n < CH_) {
                int oc = (n < 18) ? (it * 18 + n) : (54 + it * NUM_ + (n - 18));
                v = conv_w[(size_t)(oc * CH_ + ic) * 9 + tapi];
            }
            v8[j] = (__bf16)v;
        }
        *(bf16x8*)(wlin + (size_t)idx * 8) = *(const bf16x8*)v8;
    }

    gg.sync();

    // ---- 3 propagation epochs ----
    for (int iter = 0; iter < 3; ++iter) {
        const float* cur_all = (iter == 0) ? input : (inter + (size_t)(iter - 1) * PIX_);
        float* dst = inter + (size_t)iter * PIX_;

        if (tid < CH_) {
            int n = tid;
            int oc = (n < 18) ? (iter * 18 + n) : (54 + iter * NUM_ + (n - 18));
            sBias[tid] = conv_b[oc];
        }
        if (tid >= 64 && tid < 64 + 18) sTap[tid - 64] = tap[tid - 64];

        const __bf16* wbase = wlin + ((size_t)iter * 18 * 64 + lane) * 8;

        for (int t = brank; t < NTILES; t += nb) {
            int b   = t / (38 * 30);
            int r   = t - b * (38 * 30);
            int tyi = r / 38;
            int txi = r - tyi * 38;
            const int tileX0 = txi * TX;
            const int tileY0 = tyi * TY;

            const int x = tileX0 + (tid & 31);
            const int y = tileY0 + (tid >> 5);
            const int pix = b * (H_ * W_) + y * W_ + x;

            const float cpix  = confidence[pix];
            const float sppix = sp_dep[pix];
            const float inpix = input[pix];

            // stage guide tile (zero halo) as [10][34][CHL] bf16 from gt
            for (int idx = tid; idx < NPX * 4; idx += 256) {
                int chunk = idx & 3;
                int p = idx >> 2;
                int row = p / HALO_W;
                int px = p - row * HALO_W;
                int gy = tileY0 + row - 1;
                int gx = tileX0 + px - 1;
                uint4 v = make_uint4(0, 0, 0, 0);
                if (gx >= 0 && gx < W_ && gy >= 0 && gy < H_) {
                    size_t pg = (size_t)b * (H_ * W_) + (size_t)gy * W_ + gx;
                    v = ((const uint4*)(gt + pg * CHP))[chunk];
                }
                *(uint4*)((char*)sG + ((size_t)(row * HALO_W + px) * CHL + chunk * 8) * 2) = v;
            }

            f32x16 acc0 = {0,0,0,0,0,0,0,0,0,0,0,0,0,0,0,0};
            f32x16 acc1 = {0,0,0,0,0,0,0,0,0,0,0,0,0,0,0,0};

            __syncthreads();

            // MFMA main loop: 24 ds_read_b128 + 36 MFMAs per wave
            #pragma unroll
            for (int kw = 0; kw < 3; ++kw) {
                #pragma unroll
                for (int ks = 0; ks < 2; ++ks) {
                    bf16x8 A4[4];
                    #pragma unroll
                    for (int d = 0; d < 4; ++d) {
                        const __bf16* ap = sG + (size_t)((2 * w + d) * HALO_W + xl + kw) * CHL
                                         + ks * 16 + half * 8;
                        A4[d] = *(const bf16x8*)ap;
                    }
                    #pragma unroll
                    for (int kh = 0; kh < 3; ++kh) {
                        int tt = kh * 3 + kw;
                        bf16x8 Bf = *(const bf16x8*)(wbase + (size_t)(tt * 2 + ks) * 64 * 8);
                        acc0 = __builtin_amdgcn_mfma_f32_32x32x16_bf16(A4[kh],     Bf, acc0, 0, 0, 0);
                        acc1 = __builtin_amdgcn_mfma_f32_32x32x16_bf16(A4[kh + 1], Bf, acc1, 0, 0, 0);
                    }
                }
            }

            __syncthreads();   // sG reads done before aliased sC writes

            // scatter C -> sC pixel-major [256][27]
            if (xl < CH_) {
                #pragma unroll
                for (int a = 0; a < 2; ++a) {
                    const f32x16 A = a ? acc1 : acc0;
                    int ra = 2 * w + a;
                    #pragma unroll
                    for (int rr = 0; rr < 16; ++rr) {
                        int px_x = (rr & 3) + 8 * (rr >> 2) + 4 * half;
                        sC[(ra * 32 + px_x) * SCS + xl] = A[rr];
                    }
                }
            }

            __syncthreads();

            float v27[CH_];
            #pragma unroll
            for (int j = 0; j < CH_; ++j) v27[j] = sC[tid * SCS + j] + sBias[j];

            float m = v27[18];
            #pragma unroll
            for (int n = 1; n < 9; ++n) m = fmaxf(m, v27[18 + n]);
            float a9[9]; float s = 0.f;
            #pragma unroll
            for (int n = 0; n < 9; ++n) { a9[n] = __expf(v27[18 + n] - m); s += a9[n]; }
            const float inv_s = 1.f / s;

            const float* cur = cur_all + (size_t)b * (H_ * W_);
            float agg = 0.f;
            #pragma unroll
            for (int n = 0; n < 9; ++n) {
                float px = v27[2 * n]     + sTap[2 * n]     + (float)x;
                float py = v27[2 * n + 1] + sTap[2 * n + 1] + (float)y;
                float x0f = floorf(px), y0f = floorf(py);
                float wx = px - x0f, wy = py - y0f;
                int x0 = (int)x0f, y0 = (int)y0f;
                int cx0 = min(max(x0, 0), W_ - 1), cx1 = min(max(x0 + 1, 0), W_ - 1);
                int cy0 = min(max(y0, 0), H_ - 1), cy1 = min(max(y0 + 1, 0), H_ - 1);
                float mx0 = (x0 >= 0 && x0 < W_) ? 1.f : 0.f;
                float mx1 = (x0 + 1 >= 0 && x0 + 1 < W_) ? 1.f : 0.f;
                float my0 = (y0 >= 0 && y0 < H_) ? 1.f : 0.f;
                float my1 = (y0 + 1 >= 0 && y0 + 1 < H_) ? 1.f : 0.f;
                const float* r0 = cur + (size_t)cy0 * W_;
                const float* r1 = cur + (size_t)cy1 * W_;
                float v00 = r0[cx0] * (mx0 * my0);
                float v01 = r0[cx1] * (mx1 * my0);
                float v10 = r1[cx0] * (mx0 * my1);
                float v11 = r1[cx1] * (mx1 * my1);
                float val = (1.f - wy) * ((1.f - wx) * v00 + wx * v01)
                          +        wy  * ((1.f - wx) * v10 + wx * v11);
                agg = fmaf(val, a9[n] * inv_s, agg);
            }

            float sgn = (sppix > 0.f) ? 1.f : ((sppix < 0.f) ? -1.f : 0.f);
            float conf = sgn / (1.f + __expf(-cpix));
            float nc = (1.f - conf) * agg + conf * sppix;

            dst[pix] = nc;
            if (iter == 2) pred[pix] = nc;
            if (iter == 0) feat[pix] = inpix;

            __syncthreads();   // sC reads done before next tile's sG writes
        }

        if (iter < 2) gg.sync();
    }
}

// ---------------------------------------------------------------------------
// Fallback path = round-4 kernels (known-good, 216 us)
// ---------------------------------------------------------------------------
__global__ __launch_bounds__(256) void transpose_guide(
    const float* __restrict__ guide, __bf16* __restrict__ gt)
{
    int pix = blockIdx.x * 256 + threadIdx.x;
    if (pix >= PIX_) return;
    int b = pix / (H_ * W_);
    int off = pix - b * (H_ * W_);
    __align__(16) __bf16 tmp[CHP];
    const float* src = guide + (size_t)b * CH_ * H_ * W_ + off;
    #pragma unroll
    for (int ic = 0; ic < CH_; ++ic)
        tmp[ic] = (__bf16)src[(size_t)ic * (H_ * W_)];
    #pragma unroll
    for (int ic = CH_; ic < CHP; ++ic) tmp[ic] = (__bf16)0.f;
    bf16x8* dst = (bf16x8*)(gt + (size_t)pix * CHP);
    const bf16x8* s8 = (const bf16x8*)tmp;
    #pragma unroll
    for (int c = 0; c < 4; ++c) dst[c] = s8[c];
}

__global__ __launch_bounds__(256) void prep_weights(
    const float* __restrict__ conv_w, __bf16* __restrict__ wlin)
{
    int idx = blockIdx.x * 256 + threadIdx.x;
    if (idx >= 3 * 9 * 2 * 64) return;
    int lane = idx & 63;
    int grp = idx >> 6;
    int ks = grp & 1;
    int tapi = (grp >> 1) % 9;
    int it = (grp >> 1) / 9;
    int n = lane & 31;
    int half = lane >> 5;
    __align__(16) __bf16 v8[8];
    #pragma unroll
    for (int j = 0; j < 8; ++j) {
        int ic = ks * 16 + half * 8 + j;
        float v = 0.f;
        if (ic < CH_ && n < CH_) {
            int oc = (n < 18) ? (it * 18 + n) : (54 + it * NUM_ + (n - 18));
            v = conv_w[(size_t)(oc * CH_ + ic) * 9 + tapi];
        }
        v8[j] = (__bf16)v;
    }
    *(bf16x8*)(wlin + (size_t)idx * 8) = *(const bf16x8*)v8;
}

__global__ __launch_bounds__(256, 4) void dyspn_iter_mfma(
    const __bf16* __restrict__ gt, const __bf16* __restrict__ wlin,
    const float* __restrict__ conv_b, const float* __restrict__ tap,
    const float* __restrict__ confidence, const float* __restrict__ sp_dep,
    const float* __restrict__ cur_in, float* __restrict__ out_cur,
    float* __restrict__ pred, float* __restrict__ feat,
    const float* __restrict__ input, int iter)
{
    __shared__ __align__(16) char smem[256 * SCS * 4];
    __bf16* sG = (__bf16*)smem;
    float*  sC = (float*)smem;
    __shared__ float sBias[CH_ + 1];
    __shared__ float sTap[18];

    const int tid = threadIdx.x;
    const int lane = tid & 63;
    const int w = tid >> 6;
    const int xl = lane & 31;
    const int half = lane >> 5;
    const int tileX0 = blockIdx.x * TX;
    const int tileY0 = blockIdx.y * TY;
    const int b = blockIdx.z;

    const int x = tileX0 + (tid & 31);
    const int y = tileY0 + (tid >> 5);
    const int pix = b * (H_ * W_) + y * W_ + x;

    const float cpix  = confidence[pix];
    const float sppix = sp_dep[pix];
    const float inpix = input[pix];

    if (tid < CH_) {
        int n = tid;
        int oc = (n < 18) ? (iter * 18 + n) : (54 + iter * NUM_ + (n - 18));
        sBias[tid] = conv_b[oc];
    }
    if (tid >= 64 && tid < 64 + 18) sTap[tid - 64] = tap[tid - 64];

    for (int idx = tid; idx < NPX * 4; idx += 256) {
        int chunk = idx & 3;
        int p = idx >> 2;
        int row = p / HALO_W;
        int px = p - row * HALO_W;
        int gy = tileY0 + row - 1;
        int gx = tileX0 + px - 1;
        uint4 v = make_uint4(0, 0, 0, 0);
        if (gx >= 0 && gx < W_ && gy >= 0 && gy < H_) {
            size_t pg = (size_t)b * (H_ * W_) + (size_t)gy * W_ + gx;
            v = ((const uint4*)(gt + pg * CHP))[chunk];
        }
        *(uint4*)((char*)sG + ((size_t)(row * HALO_W + px) * CHL + chunk * 8) * 2) = v;
    }

    f32x16 acc0 = {0,0,0,0,0,0,0,0,0,0,0,0,0,0,0,0};
    f32x16 acc1 = {0,0,0,0,0,0,0,0,0,0,0,0,0,0,0,0};

    __syncthreads();

    const __bf16* wbase = wlin + ((size_t)iter * 18 * 64 + lane) * 8;
    #pragma unroll
    for (int kw = 0; kw < 3; ++kw) {
        #pragma unroll
        for (int ks = 0; ks < 2; ++ks) {
            bf16x8 A4[4];
            #pragma unroll
            for (int d = 0; d < 4; ++d) {
                const __bf16* ap = sG + (size_t)((2 * w + d) * HALO_W + xl + kw) * CHL
                                 + ks * 16 + half * 8;
                A4[d] = *(const bf16x8*)ap;
            }
            #pragma unroll
            for (int kh = 0; kh < 3; ++kh) {
                int t = kh * 3 + kw;
                bf16x8 Bf = *(const bf16x8*)(wbase + (size_t)(t * 2 + ks) * 64 * 8);
                acc0 = __builtin_amdgcn_mfma_f32_32x32x16_bf16(A4[kh],     Bf, acc0, 0, 0, 0);
                acc1 = __builtin_amdgcn_mfma_f32_32x32x16_bf16(A4[kh + 1], Bf, acc1, 0, 0, 0);
            }
        }
    }

    __syncthreads();

    if (xl < CH_) {
        #pragma unroll
        for (int a = 0; a < 2; ++a) {
            const f32x16 A = a ? acc1 : acc0;
            int ra = 2 * w + a;
            #pragma unroll
            for (int r = 0; r < 16; ++r) {
                int px_x = (r & 3) + 8 * (r >> 2) + 4 * half;
                sC[(ra * 32 + px_x) * SCS + xl] = A[r];
            }
        }
    }

    __syncthreads();

    float v27[CH_];
    #pragma unroll
    for (int j = 0; j < CH_; ++j) v27[j] = sC[tid * SCS + j] + sBias[j];

    float m = v27[18];
    #pragma unroll
    for (int n = 1; n < 9; ++n) m = fmaxf(m, v27[18 + n]);
    float a9[9]; float s = 0.f;
    #pragma unroll
    for (int n = 0; n < 9; ++n) { a9[n] = __expf(v27[18 + n] - m); s += a9[n]; }
    const float inv_s = 1.f / s;

    const float* cur = cur_in + (size_t)b * (H_ * W_);
    float agg = 0.f;
    #pragma unroll
    for (int n = 0; n < 9; ++n) {
        float px = v27[2 * n]     + sTap[2 * n]     + (float)x;
        float py = v27[2 * n + 1] + sTap[2 * n + 1] + (float)y;
        float x0f = floorf(px), y0f = floorf(py);
        float wx = px - x0f, wy = py - y0f;
        int x0 = (int)x0f, y0 = (int)y0f;
        int cx0 = min(max(x0, 0), W_ - 1), cx1 = min(max(x0 + 1, 0), W_ - 1);
        int cy0 = min(max(y0, 0), H_ - 1), cy1 = min(max(y0 + 1, 0), H_ - 1);
        float mx0 = (x0 >= 0 && x0 < W_) ? 1.f : 0.f;
        float mx1 = (x0 + 1 >= 0 && x0 + 1 < W_) ? 1.f : 0.f;
        float my0 = (y0 >= 0 && y0 < H_) ? 1.f : 0.f;
        float my1 = (y0 + 1 >= 0 && y0 + 1 < H_) ? 1.f : 0.f;
        const float* r0 = cur + (size_t)cy0 * W_;
        const float* r1 = cur + (size_t)cy1 * W_;
        float v00 = r0[cx0] * (mx0 * my0);
        float v01 = r0[cx1] * (mx1 * my0);
        float v10 = r1[cx0] * (mx0 * my1);
        float v11 = r1[cx1] * (mx1 * my1);
        float val = (1.f - wy) * ((1.f - wx) * v00 + wx * v01)
                  +        wy  * ((1.f - wx) * v10 + wx * v11);
        agg = fmaf(val, a9[n] * inv_s, agg);
    }

    float sgn = (sppix > 0.f) ? 1.f : ((sppix < 0.f) ? -1.f : 0.f);
    float conf = sgn / (1.f + __expf(-cpix));
    float nc = (1.f - conf) * agg + conf * sppix;

    out_cur[pix] = nc;
    if (pred) pred[pix] = nc;
    if (feat) feat[pix] = inpix;
}

extern "C" void kernel_launch(void* const* d_in, const int* in_sizes, int n_in,
                              void* d_out, int out_size, void* d_ws, size_t ws_size,
                              hipStream_t stream) {
    (void)in_sizes; (void)n_in; (void)out_size;
    const float* input      = (const float*)d_in[0];
    const float* guide      = (const float*)d_in[1];
    const float* sp_dep     = (const float*)d_in[2];
    const float* confidence = (const float*)d_in[3];
    const float* conv_w     = (const float*)d_in[4];
    const float* conv_b     = (const float*)d_in[5];
    const float* tap        = (const float*)d_in[6];

    float* out   = (float*)d_out;
    const int P  = PIX_;
    float* pred  = out;           // [B,1,H,W]
    float* feat  = out + P;       // [B,1,H,W]
    float* inter = out + 2 * P;   // [ITER,B,1,H,W]

    const size_t gt_bytes   = (size_t)PIX_ * CHP * 2;          // 37,355,520
    const size_t wlin_bytes = (size_t)3 * 9 * 2 * 64 * 8 * 2;  // 55,296

    __bf16* gt   = (__bf16*)d_ws;
    __bf16* wlin = (__bf16*)((char*)d_ws + gt_bytes);

    // Query the driver's real cooperative co-residency capacity (host-side,
    // deterministic, graph-capture-safe).
    int dev = 0;
    (void)hipGetDevice(&dev);
    int numCU = 0;
    (void)hipDeviceGetAttribute(&numCU, hipDeviceAttributeMultiprocessorCount, dev);
    int maxPerCU = 0;
    (void)hipOccupancyMaxActiveBlocksPerMultiprocessor(&maxPerCU, dyspn_persistent, 256, 0);
    long cap = (long)maxPerCU * (long)numCU;

    bool haveWs = ws_size >= gt_bytes + wlin_bytes;

    if (haveWs && cap >= 256) {
        // balanced grid choice: 1140 (2 tiles/blk) > 760 (3 tiles/blk) > cap
        int gp = (cap >= 1140) ? 1140 : ((cap >= 760) ? 760 : (int)cap);
        void* args[] = { (void*)&guide, (void*)&conv_w, (void*)&conv_b,
                         (void*)&tap, (void*)&confidence, (void*)&sp_dep,
                         (void*)&input, (void*)&pred, (void*)&feat,
                         (void*)&inter, (void*)&gt, (void*)&wlin };
        hipError_t e = hipLaunchCooperativeKernel((const void*)dyspn_persistent,
                                                  dim3(gp), dim3(256), args, 0, stream);
        if (e == hipSuccess) return;
        // fall through to multi-dispatch path on rejection
    }

    if (haveWs) {
        transpose_guide<<<(PIX_ + 255) / 256, 256, 0, stream>>>(guide, gt);
        prep_weights<<<(3 * 9 * 2 * 64 + 255) / 256, 256, 0, stream>>>(conv_w, wlin);
        dim3 grid(W_ / TX, H_ / TY, B_);
        for (int i = 0; i < 3; ++i) {
            const float* cur = (i == 0) ? input : (inter + (i - 1) * P);
            dyspn_iter_mfma<<<grid, 256, 0, stream>>>(
                gt, wlin, conv_b, tap, confidence, sp_dep,
                cur, inter + i * P,
                (i == 2) ? pred : nullptr,
                (i == 0) ? feat : nullptr,
                input, i);
        }
    }
}